// Round 6
// baseline (870.325 us; speedup 1.0000x reference)
//
#include <hip/hip_runtime.h>

typedef __attribute__((ext_vector_type(8))) short bf16x8;
typedef __attribute__((ext_vector_type(4))) float f32x4;

__device__ __forceinline__ short f2b(float f) {
  unsigned u = __builtin_bit_cast(unsigned, f);
  unsigned r = (u + 0x7FFFu + ((u >> 16) & 1u)) >> 16;
  return (short)r;
}
__device__ __forceinline__ float b2f(short s) {
  unsigned u = ((unsigned)(unsigned short)s) << 16;
  return __builtin_bit_cast(float, u);
}

__device__ __forceinline__ void gload16(const void* g, void* l) {
  __builtin_amdgcn_global_load_lds(
      (const __attribute__((address_space(1))) void*)g,
      (__attribute__((address_space(3))) void*)l, 16, 0, 0);
}

// tanh-form GELU: |err| vs erf-GELU < ~5e-4, far under bf16 rounding.
__device__ __forceinline__ float gelu_f(float v) {
  float u = v * (0.7978845608f + 0.0356774081f * v * v);
  float a = fabsf(u);
  float e = __expf(-2.f * a);
  float t = (1.f - e) * __builtin_amdgcn_rcpf(1.f + e);
  t = (u < 0.f) ? -t : t;
  return 0.5f * v * (1.f + t);
}

// ---------------- packing kernels ----------------
__global__ void cvt_bf16_vec(const float* __restrict__ src, short* __restrict__ dst, long n) {
  long i = ((long)blockIdx.x * 256 + threadIdx.x) * 8;
  if (i >= n) return;
  f32x4 a = *(const f32x4*)(src + i);
  f32x4 b = *(const f32x4*)(src + i + 4);
  bf16x8 o;
#pragma unroll
  for (int j = 0; j < 4; j++) o[j] = f2b(a[j]);
#pragma unroll
  for (int j = 0; j < 4; j++) o[j + 4] = f2b(b[j]);
  *(bf16x8*)(dst + i) = o;
}

// dst[n][k] = bf16(src[k][n]); both sides coalesced via 32x33 LDS tile.
__global__ void transpose_cvt_t(const float* __restrict__ src, short* __restrict__ dst,
                                int K, int N) {
  __shared__ float tile[32][33];
  const int n0 = blockIdx.x * 32, k0 = blockIdx.y * 32;
  const int j = threadIdx.x & 31, i0 = threadIdx.x >> 5;
#pragma unroll
  for (int r = 0; r < 4; r++) {
    int i = i0 + r * 8;
    tile[i][j] = src[(long)(k0 + i) * N + n0 + j];
  }
  __syncthreads();
#pragma unroll
  for (int r = 0; r < 4; r++) {
    int i = i0 + r * 8;
    dst[(long)(n0 + i) * K + k0 + j] = f2b(tile[j][i]);
  }
}

__global__ void pack_bias3(const float* __restrict__ b0, const float* __restrict__ b1,
                           const float* __restrict__ b2, float* __restrict__ out) {
  int t = blockIdx.x * 256 + threadIdx.x;
  if (t >= 1536) return;
  out[t] = (t < 512) ? b0[t] : ((t < 1024) ? b1[t - 512] : b2[t - 1024]);
}

// ---------------- GEMM: C = A[M][K] @ Bt[N][K]^T  (both bf16) ----------------
// 128x128 tile, BK=32. 5-buffer LDS ring (80 KiB), stage distance 4,
// counted s_waitcnt vmcnt(12) (never 0 in-loop), ONE barrier per K-tile.
// Chunk-XOR swizzle (chunk' = chunk ^ (row&3)): pre-swizzled per-lane global
// SOURCE (linear gload_lds dest) + same XOR on ds_read offsets -> no bank
// conflicts (proven correct+conflict-free in round 3).
// EPI 0: bf16 v+bias (QKV) | 1: bf16 gelu(v+bias) (fc1)
// EPI 2: f32 v+bias+resF (proj+x) | 3: f32 v+bias+resB (fc2+h, bf16 res)
template <int EPI>
__global__ __launch_bounds__(256, 2) void gemm_bt(
    const short* __restrict__ A, const short* __restrict__ Bt,
    const float* __restrict__ bias, const float* __restrict__ resF,
    const short* __restrict__ resB, void* __restrict__ Cout, int K, int ldc, int gxN) {
  __shared__ short lds[5 * 8192];  // per buffer: A 4096 shorts | B 4096 shorts
  const int t = threadIdx.x;
  const int w = t >> 6, lane = t & 63;
  const int lr = lane & 15, lg = lane >> 4;

  const int nwg = gridDim.x;
  const int orig = blockIdx.x;
  const int q = nwg >> 3, r = nwg & 7, xcd = orig & 7, idx = orig >> 3;
  const int swz = (xcd < r ? xcd * (q + 1) : r * (q + 1) + (xcd - r) * q) + idx;
  const long m0 = (long)(swz / gxN) * 128;
  const int n0 = (swz % gxN) * 128;

  const int wm = (w >> 1) * 64, wn = (w & 1) * 64;

  f32x4 acc[4][4];
#pragma unroll
  for (int i = 0; i < 4; i++)
#pragma unroll
    for (int j = 0; j < 4; j++) acc[i][j] = f32x4{0.f, 0.f, 0.f, 0.f};

  // staging: thread t covers (row = t>>2 [+64], chunk = t&3); pre-swizzled
  // source chunk = (t&3) ^ ((t>>2)&3)  [row&3 == (t>>2)&3 for both halves].
  const int srow = t >> 2;
  const int schunk = (t & 3) ^ ((t >> 2) & 3);
  const short* Ag = A + (m0 + srow) * (long)K + schunk * 8;
  const short* Bg = Bt + ((long)n0 + srow) * K + schunk * 8;
  const long half = (long)64 * K;

#define STAGE(b, kt)                                   \
  {                                                    \
    short* d = lds + (b) * 8192 + t * 8;               \
    gload16(Ag + (long)(kt) * 32, d);                  \
    gload16(Ag + half + (long)(kt) * 32, d + 2048);    \
    gload16(Bg + (long)(kt) * 32, d + 4096);           \
    gload16(Bg + half + (long)(kt) * 32, d + 6144);    \
  }

  // read offsets with matching XOR (row&3 == lr&3; wm/wn/mi are mult of 16)
  const int xsw = (lg ^ (lr & 3)) * 8;
  const int aoff = (wm + lr) * 32 + xsw;
  const int boff = 4096 + (wn + lr) * 32 + xsw;

#define TILE_WAIT(WN)                                        \
  asm volatile("s_waitcnt vmcnt(" #WN ")" ::: "memory");     \
  __builtin_amdgcn_sched_barrier(0);                         \
  __builtin_amdgcn_s_barrier();                              \
  __builtin_amdgcn_sched_barrier(0);

#define BODY(CB)                                                               \
  {                                                                            \
    const short* Lb = lds + (CB) * 8192;                                       \
    bf16x8 a[4], b[4];                                                         \
    _Pragma("unroll") for (int mi = 0; mi < 4; mi++)                           \
        a[mi] = *(const bf16x8*)(Lb + aoff + mi * 512);                        \
    _Pragma("unroll") for (int nj = 0; nj < 4; nj++)                           \
        b[nj] = *(const bf16x8*)(Lb + boff + nj * 512);                        \
    __builtin_amdgcn_s_setprio(1);                                             \
    _Pragma("unroll") for (int mi = 0; mi < 4; mi++)                           \
        _Pragma("unroll") for (int nj = 0; nj < 4; nj++) acc[mi][nj] =         \
            __builtin_amdgcn_mfma_f32_16x16x32_bf16(a[mi], b[nj], acc[mi][nj], \
                                                    0, 0, 0);                  \
    __builtin_amdgcn_s_setprio(0);                                             \
  }

  const int NKT = K >> 5;  // >= 16 for all our shapes
  STAGE(0, 0) STAGE(1, 1) STAGE(2, 2) STAGE(3, 3)

  int cb = 0, sb = 4;
  for (int kt = 0; kt < NKT - 4; ++kt) {
    TILE_WAIT(12)
    STAGE(sb, kt + 4)
    BODY(cb)
    cb = (cb == 4) ? 0 : cb + 1;
    sb = (sb == 4) ? 0 : sb + 1;
  }
  TILE_WAIT(12) BODY(cb) cb = (cb == 4) ? 0 : cb + 1;
  TILE_WAIT(8)  BODY(cb) cb = (cb == 4) ? 0 : cb + 1;
  TILE_WAIT(4)  BODY(cb) cb = (cb == 4) ? 0 : cb + 1;
  TILE_WAIT(0)  BODY(cb)
#undef STAGE
#undef TILE_WAIT
#undef BODY

  // epilogue: bias hoisted (4 loads), row base hoisted per (mi,i)
  float bv[4];
#pragma unroll
  for (int nj = 0; nj < 4; nj++) bv[nj] = bias[n0 + wn + nj * 16 + lr];

#pragma unroll
  for (int mi = 0; mi < 4; mi++)
#pragma unroll
    for (int i = 0; i < 4; i++) {
      const long row = m0 + wm + mi * 16 + lg * 4 + i;
      const long rb = row * ldc + n0 + wn + lr;
      if (EPI == 0) {
        short* p = (short*)Cout + rb;
#pragma unroll
        for (int nj = 0; nj < 4; nj++) p[nj * 16] = f2b(acc[mi][nj][i] + bv[nj]);
      } else if (EPI == 1) {
        short* p = (short*)Cout + rb;
#pragma unroll
        for (int nj = 0; nj < 4; nj++) p[nj * 16] = f2b(gelu_f(acc[mi][nj][i] + bv[nj]));
      } else if (EPI == 2) {
        float* p = (float*)Cout + rb;
        const float* rp = resF + rb;
#pragma unroll
        for (int nj = 0; nj < 4; nj++) p[nj * 16] = acc[mi][nj][i] + bv[nj] + rp[nj * 16];
      } else {
        float* p = (float*)Cout + rb;
        const short* rp = resB + rb;
#pragma unroll
        for (int nj = 0; nj < 4; nj++)
          p[nj * 16] = acc[mi][nj][i] + bv[nj] + b2f(rp[nj * 16]);
      }
    }
}

// ---------------- windowed attention ----------------
__global__ __launch_bounds__(256, 2) void attn_win(const short* __restrict__ QKV,
                                                   short* __restrict__ AO) {
  __shared__ short Vs[64 * 72];
  __shared__ short Ps[64 * 72];
  const int t = threadIdx.x, w = t >> 6, lane = t & 63;
  const int lr = lane & 15, lg = lane >> 4;
  const long base = (long)blockIdx.x * 64 * 1536;
  const long obase = (long)blockIdx.x * 64 * 512;

  for (int h = 0; h < 8; h++) {
    const int co = h * 64;
#pragma unroll
    for (int it = 0; it < 2; it++) {
      int c = t + it * 256;
      int j = c >> 3, d0 = (c & 7) * 8;
      *(bf16x8*)(Vs + j * 72 + d0) =
          *(const bf16x8*)(QKV + base + (long)j * 1536 + 1024 + co + d0);
    }
    __syncthreads();

    bf16x8 qf[2], kf[4][2];
#pragma unroll
    for (int kb = 0; kb < 2; kb++)
      qf[kb] = *(const bf16x8*)(QKV + base + (long)(w * 16 + lr) * 1536 + co + kb * 32 + lg * 8);
#pragma unroll
    for (int nj = 0; nj < 4; nj++)
#pragma unroll
      for (int kb = 0; kb < 2; kb++)
        kf[nj][kb] = *(const bf16x8*)(QKV + base + (long)(nj * 16 + lr) * 1536 + 512 + co +
                                      kb * 32 + lg * 8);

    f32x4 s[4];
#pragma unroll
    for (int nj = 0; nj < 4; nj++) {
      s[nj] = f32x4{0.f, 0.f, 0.f, 0.f};
      s[nj] = __builtin_amdgcn_mfma_f32_16x16x32_bf16(qf[0], kf[nj][0], s[nj], 0, 0, 0);
      s[nj] = __builtin_amdgcn_mfma_f32_16x16x32_bf16(qf[1], kf[nj][1], s[nj], 0, 0, 0);
      s[nj] = s[nj] * 0.125f;
    }

#pragma unroll
    for (int i = 0; i < 4; i++) {
      float mx = fmaxf(fmaxf(s[0][i], s[1][i]), fmaxf(s[2][i], s[3][i]));
#pragma unroll
      for (int off = 1; off < 16; off <<= 1) mx = fmaxf(mx, __shfl_xor(mx, off, 64));
      float sum = 0.f;
#pragma unroll
      for (int nj = 0; nj < 4; nj++) {
        float p = __expf(s[nj][i] - mx);
        s[nj][i] = p;
        sum += p;
      }
#pragma unroll
      for (int off = 1; off < 16; off <<= 1) sum += __shfl_xor(sum, off, 64);
      float inv = 1.f / sum;
#pragma unroll
      for (int nj = 0; nj < 4; nj++) s[nj][i] *= inv;
    }

#pragma unroll
    for (int nj = 0; nj < 4; nj++)
#pragma unroll
      for (int i = 0; i < 4; i++)
        Ps[(w * 16 + lg * 4 + i) * 72 + nj * 16 + lr] = f2b(s[nj][i]);

    bf16x8 pa[2];
#pragma unroll
    for (int kb = 0; kb < 2; kb++)
      pa[kb] = *(const bf16x8*)(Ps + (w * 16 + lr) * 72 + kb * 32 + lg * 8);

    f32x4 o[4];
#pragma unroll
    for (int nb = 0; nb < 4; nb++) o[nb] = f32x4{0.f, 0.f, 0.f, 0.f};
#pragma unroll
    for (int kb = 0; kb < 2; kb++)
#pragma unroll
      for (int nb = 0; nb < 4; nb++) {
        bf16x8 vb;
#pragma unroll
        for (int jj = 0; jj < 8; jj++)
          vb[jj] = Vs[(kb * 32 + lg * 8 + jj) * 72 + nb * 16 + lr];
        o[nb] = __builtin_amdgcn_mfma_f32_16x16x32_bf16(pa[kb], vb, o[nb], 0, 0, 0);
      }

#pragma unroll
    for (int nb = 0; nb < 4; nb++)
#pragma unroll
      for (int i = 0; i < 4; i++)
        AO[obase + (long)(w * 16 + lg * 4 + i) * 512 + co + nb * 16 + lr] = f2b(o[nb][i]);
    __syncthreads();
  }
}

// ---------------- LayerNorm over C=512, one row per wave ----------------
template <int OUTB>
__global__ __launch_bounds__(256, 4) void ln_rows(const float* __restrict__ Y,
                                                  const float* __restrict__ gamma,
                                                  const float* __restrict__ beta,
                                                  short* __restrict__ Hb,
                                                  float* __restrict__ Of) {
  const int w = threadIdx.x >> 6, lane = threadIdx.x & 63;
  const long row = (long)blockIdx.x * 4 + w;
  const float* y = Y + row * 512 + lane * 8;
  f32x4 a = *(const f32x4*)(y);
  f32x4 b = *(const f32x4*)(y + 4);
  float s = a[0] + a[1] + a[2] + a[3] + b[0] + b[1] + b[2] + b[3];
  float s2 = a[0] * a[0] + a[1] * a[1] + a[2] * a[2] + a[3] * a[3] + b[0] * b[0] +
             b[1] * b[1] + b[2] * b[2] + b[3] * b[3];
#pragma unroll
  for (int off = 1; off < 64; off <<= 1) {
    s += __shfl_xor(s, off, 64);
    s2 += __shfl_xor(s2, off, 64);
  }
  float mu = s * (1.f / 512.f);
  float var = s2 * (1.f / 512.f) - mu * mu;
  float rstd = rsqrtf(fmaxf(var, 0.f) + 1e-12f);
  const int c0 = lane * 8;
  f32x4 ga = *(const f32x4*)(gamma + c0), gb = *(const f32x4*)(gamma + c0 + 4);
  f32x4 ba = *(const f32x4*)(beta + c0), bb = *(const f32x4*)(beta + c0 + 4);
  if (OUTB) {
    bf16x8 o;
#pragma unroll
    for (int j = 0; j < 4; j++) o[j] = f2b(ga[j] * ((a[j] - mu) * rstd) + ba[j]);
#pragma unroll
    for (int j = 0; j < 4; j++) o[j + 4] = f2b(gb[j] * ((b[j] - mu) * rstd) + bb[j]);
    *(bf16x8*)(Hb + row * 512 + c0) = o;
  } else {
    f32x4 o0, o1;
#pragma unroll
    for (int j = 0; j < 4; j++) o0[j] = ga[j] * ((a[j] - mu) * rstd) + ba[j];
#pragma unroll
    for (int j = 0; j < 4; j++) o1[j] = gb[j] * ((b[j] - mu) * rstd) + bb[j];
    *(f32x4*)(Of + row * 512 + c0) = o0;
    *(f32x4*)(Of + row * 512 + c0 + 4) = o1;
  }
}

// ---------------- driver ----------------
extern "C" void kernel_launch(void* const* d_in, const int* in_sizes, int n_in,
                              void* d_out, int out_size, void* d_ws, size_t ws_size,
                              hipStream_t stream) {
  (void)in_sizes; (void)n_in; (void)out_size;
  const float* x = (const float*)d_in[0];
  const float* wq = (const float*)d_in[1];
  const float* bq = (const float*)d_in[2];
  const float* wk = (const float*)d_in[3];
  const float* bk = (const float*)d_in[4];
  const float* wv = (const float*)d_in[5];
  const float* bv = (const float*)d_in[6];
  const float* wo = (const float*)d_in[7];
  const float* bo = (const float*)d_in[8];
  const float* g1 = (const float*)d_in[9];
  const float* be1 = (const float*)d_in[10];
  const float* wfc1 = (const float*)d_in[11];
  const float* bfc1 = (const float*)d_in[12];
  const float* wfc2 = (const float*)d_in[13];
  const float* bfc2 = (const float*)d_in[14];
  const float* g2 = (const float*)d_in[15];
  const float* be2 = (const float*)d_in[16];

  const long T = 65536;
  char* ws = (char*)d_ws;

  // ---- weights at offset 0 (~6.3 MiB) ----
  short* WQKVT = (short*)(ws);                 // [1536][512]
  short* WOT = WQKVT + 1536 * 512;             // [512][512]
  short* WFC1T = WOT + 512 * 512;              // [2048][512]
  short* WFC2T = WFC1T + 2048 * 512;           // [512][2048]
  float* BQKV = (float*)(WFC2T + 512 * 2048);  // [1536]
  size_t woff = ((size_t)((char*)(BQKV + 1536) - ws) + 255) & ~(size_t)255;

  // ---- adaptive chunking (Tc multiple of 128) ----
  size_t avail = (ws_size > woff) ? (ws_size - woff) : 0;
  long Tc = T;
  while (Tc > 128 && (size_t)Tc * 7168 > avail) Tc >>= 1;
  const long nch = T / Tc;

  char* R0 = ws + woff;               // QKV bf16 [Tc][1536] / Y1 f32 / FF1 bf16 [Tc][2048]
  char* R1 = R0 + (size_t)Tc * 4096;  // XB bf16 / AO bf16 / Y2 f32
  char* R2 = R1 + (size_t)Tc * 2048;  // H bf16

  short* QKV = (short*)R0;
  float* Y1 = (float*)R0;
  short* FF1 = (short*)R0;
  short* XB = (short*)R1;
  short* AO = (short*)R1;
  float* Y2 = (float*)R1;
  short* H = (short*)R2;

  // ---- pack weights (tiled transposes, both sides coalesced) ----
  transpose_cvt_t<<<dim3(16, 16), 256, 0, stream>>>(wq, WQKVT, 512, 512);
  transpose_cvt_t<<<dim3(16, 16), 256, 0, stream>>>(wk, WQKVT + 512 * 512, 512, 512);
  transpose_cvt_t<<<dim3(16, 16), 256, 0, stream>>>(wv, WQKVT + 1024 * 512, 512, 512);
  transpose_cvt_t<<<dim3(16, 16), 256, 0, stream>>>(wo, WOT, 512, 512);
  transpose_cvt_t<<<dim3(64, 16), 256, 0, stream>>>(wfc1, WFC1T, 512, 2048);
  transpose_cvt_t<<<dim3(16, 64), 256, 0, stream>>>(wfc2, WFC2T, 2048, 512);
  pack_bias3<<<6, 256, 0, stream>>>(bq, bk, bv, BQKV);

  for (long c = 0; c < nch; c++) {
    const long t0 = c * Tc;
    const int mb = (int)(Tc / 128);
    cvt_bf16_vec<<<(int)(Tc / 4), 256, 0, stream>>>(x + t0 * 512, XB, Tc * 512);
    gemm_bt<0><<<mb * 12, 256, 0, stream>>>(XB, WQKVT, BQKV, nullptr, nullptr,
                                            (void*)QKV, 512, 1536, 12);
    attn_win<<<(int)(Tc / 64), 256, 0, stream>>>(QKV, AO);
    gemm_bt<2><<<mb * 4, 256, 0, stream>>>(AO, WOT, bo, x + t0 * 512, nullptr,
                                           (void*)Y1, 512, 512, 4);
    ln_rows<1><<<(int)(Tc / 4), 256, 0, stream>>>(Y1, g1, be1, H, nullptr);
    gemm_bt<1><<<mb * 16, 256, 0, stream>>>(H, WFC1T, bfc1, nullptr, nullptr,
                                            (void*)FF1, 512, 2048, 16);
    gemm_bt<3><<<mb * 4, 256, 0, stream>>>(FF1, WFC2T, bfc2, nullptr, H, (void*)Y2,
                                           2048, 512, 4);
    ln_rows<0><<<(int)(Tc / 4), 256, 0, stream>>>(Y2, g2, be2, nullptr,
                                                  (float*)d_out + t0 * 512);
  }
}

// Round 7
// 819.595 us; speedup vs baseline: 1.0619x; 1.0619x over previous
//
#include <hip/hip_runtime.h>

typedef __attribute__((ext_vector_type(8))) short bf16x8;
typedef __attribute__((ext_vector_type(4))) float f32x4;

__device__ __forceinline__ short f2b(float f) {
  unsigned u = __builtin_bit_cast(unsigned, f);
  unsigned r = (u + 0x7FFFu + ((u >> 16) & 1u)) >> 16;
  return (short)r;
}
__device__ __forceinline__ float b2f(short s) {
  unsigned u = ((unsigned)(unsigned short)s) << 16;
  return __builtin_bit_cast(float, u);
}

__device__ __forceinline__ void gload16(const void* g, void* l) {
  __builtin_amdgcn_global_load_lds(
      (const __attribute__((address_space(1))) void*)g,
      (__attribute__((address_space(3))) void*)l, 16, 0, 0);
}

// tanh-form GELU: |err| vs erf-GELU < ~5e-4, far under bf16 rounding.
__device__ __forceinline__ float gelu_f(float v) {
  float u = v * (0.7978845608f + 0.0356774081f * v * v);
  float a = fabsf(u);
  float e = __expf(-2.f * a);
  float t = (1.f - e) * __builtin_amdgcn_rcpf(1.f + e);
  t = (u < 0.f) ? -t : t;
  return 0.5f * v * (1.f + t);
}

// ---------------- packing kernels ----------------
__global__ void cvt_bf16_vec(const float* __restrict__ src, short* __restrict__ dst, long n) {
  long i = ((long)blockIdx.x * 256 + threadIdx.x) * 8;
  if (i >= n) return;
  f32x4 a = *(const f32x4*)(src + i);
  f32x4 b = *(const f32x4*)(src + i + 4);
  bf16x8 o;
#pragma unroll
  for (int j = 0; j < 4; j++) o[j] = f2b(a[j]);
#pragma unroll
  for (int j = 0; j < 4; j++) o[j + 4] = f2b(b[j]);
  *(bf16x8*)(dst + i) = o;
}

// dst[n][k] = bf16(src[k][n]); both sides coalesced via 32x33 LDS tile.
__global__ void transpose_cvt_t(const float* __restrict__ src, short* __restrict__ dst,
                                int K, int N) {
  __shared__ float tile[32][33];
  const int n0 = blockIdx.x * 32, k0 = blockIdx.y * 32;
  const int j = threadIdx.x & 31, i0 = threadIdx.x >> 5;
#pragma unroll
  for (int r = 0; r < 4; r++) {
    int i = i0 + r * 8;
    tile[i][j] = src[(long)(k0 + i) * N + n0 + j];
  }
  __syncthreads();
#pragma unroll
  for (int r = 0; r < 4; r++) {
    int i = i0 + r * 8;
    dst[(long)(n0 + i) * K + k0 + j] = f2b(tile[j][i]);
  }
}

__global__ void pack_bias3(const float* __restrict__ b0, const float* __restrict__ b1,
                           const float* __restrict__ b2, float* __restrict__ out) {
  int t = blockIdx.x * 256 + threadIdx.x;
  if (t >= 1536) return;
  out[t] = (t < 512) ? b0[t] : ((t < 1024) ? b1[t - 512] : b2[t - 1024]);
}

// ---------------- GEMM: C = A[M][K] @ Bt[N][K]^T  (both bf16) ----------------
// 128x128 tile, BK=32. 3-buffer LDS ring (48 KiB), stage distance 2,
// counted s_waitcnt vmcnt(4) (never 0 in-loop), ONE barrier per K-tile.
// Chunk-XOR swizzle chunk' = chunk ^ ((row>>1)&3)  [round-3-verified: zero
// bank conflicts]: pre-swizzled per-lane global SOURCE (linear gload_lds
// dest) + same XOR on ds_read offsets. Lanes lr and lr+8 share a bank quad
// -> 2-way = free (m136).
// EPI 0: bf16 v+bias (QKV) | 1: bf16 gelu(v+bias) (fc1)
// EPI 2: f32 v+bias+resF (proj+x) | 3: f32 v+bias+resB (fc2+h, bf16 res)
template <int EPI>
__global__ __launch_bounds__(256, 3) void gemm_bt(
    const short* __restrict__ A, const short* __restrict__ Bt,
    const float* __restrict__ bias, const float* __restrict__ resF,
    const short* __restrict__ resB, void* __restrict__ Cout, int K, int ldc, int gxN) {
  __shared__ short lds[3 * 8192];  // per buffer: A 4096 shorts | B 4096 shorts
  const int t = threadIdx.x;
  const int w = t >> 6, lane = t & 63;
  const int lr = lane & 15, lg = lane >> 4;

  const int nwg = gridDim.x;
  const int orig = blockIdx.x;
  const int q = nwg >> 3, r = nwg & 7, xcd = orig & 7, idx = orig >> 3;
  const int swz = (xcd < r ? xcd * (q + 1) : r * (q + 1) + (xcd - r) * q) + idx;
  const long m0 = (long)(swz / gxN) * 128;
  const int n0 = (swz % gxN) * 128;

  const int wm = (w >> 1) * 64, wn = (w & 1) * 64;

  f32x4 acc[4][4];
#pragma unroll
  for (int i = 0; i < 4; i++)
#pragma unroll
    for (int j = 0; j < 4; j++) acc[i][j] = f32x4{0.f, 0.f, 0.f, 0.f};

  // staging: thread t covers (row = t>>2 [+64], chunk = t&3); pre-swizzled
  // source chunk = (t&3) ^ ((row>>1)&3) = (t&3) ^ ((t>>3)&3).
  const int srow = t >> 2;
  const int schunk = (t & 3) ^ ((t >> 3) & 3);
  const short* Ag = A + (m0 + srow) * (long)K + schunk * 8;
  const short* Bg = Bt + ((long)n0 + srow) * K + schunk * 8;
  const long half = (long)64 * K;

#define STAGE(b, kt)                                   \
  {                                                    \
    short* d = lds + (b) * 8192 + t * 8;               \
    gload16(Ag + (long)(kt) * 32, d);                  \
    gload16(Ag + half + (long)(kt) * 32, d + 2048);    \
    gload16(Bg + (long)(kt) * 32, d + 4096);           \
    gload16(Bg + half + (long)(kt) * 32, d + 6144);    \
  }

  // read offsets with matching XOR; row bits 1..2 come only from lr.
  const int xsw = (lg ^ ((lr >> 1) & 3)) * 8;
  const int aoff = (wm + lr) * 32 + xsw;
  const int boff = 4096 + (wn + lr) * 32 + xsw;

#define TILE_WAIT(WN)                                        \
  asm volatile("s_waitcnt vmcnt(" #WN ")" ::: "memory");     \
  __builtin_amdgcn_sched_barrier(0);                         \
  __builtin_amdgcn_s_barrier();                              \
  __builtin_amdgcn_sched_barrier(0);

#define BODY(CB)                                                               \
  {                                                                            \
    const short* Lb = lds + (CB) * 8192;                                       \
    bf16x8 a[4], b[4];                                                         \
    _Pragma("unroll") for (int mi = 0; mi < 4; mi++)                           \
        a[mi] = *(const bf16x8*)(Lb + aoff + mi * 512);                        \
    _Pragma("unroll") for (int nj = 0; nj < 4; nj++)                           \
        b[nj] = *(const bf16x8*)(Lb + boff + nj * 512);                        \
    __builtin_amdgcn_s_setprio(1);                                             \
    _Pragma("unroll") for (int mi = 0; mi < 4; mi++)                           \
        _Pragma("unroll") for (int nj = 0; nj < 4; nj++) acc[mi][nj] =         \
            __builtin_amdgcn_mfma_f32_16x16x32_bf16(a[mi], b[nj], acc[mi][nj], \
                                                    0, 0, 0);                  \
    __builtin_amdgcn_s_setprio(0);                                             \
  }

  const int NKT = K >> 5;
  STAGE(0, 0)
  STAGE(1, 1)

  int cb = 0, sb = 2;
  for (int kt = 0; kt < NKT - 1; ++kt) {
    TILE_WAIT(4)
    if (kt + 2 < NKT) STAGE(sb, kt + 2)
    BODY(cb)
    cb = (cb == 2) ? 0 : cb + 1;
    sb = (sb == 2) ? 0 : sb + 1;
  }
  TILE_WAIT(0)
  BODY(cb)
#undef STAGE
#undef TILE_WAIT
#undef BODY

  // epilogue: bias hoisted (4 loads), row base hoisted per (mi,i)
  float bv[4];
#pragma unroll
  for (int nj = 0; nj < 4; nj++) bv[nj] = bias[n0 + wn + nj * 16 + lr];

#pragma unroll
  for (int mi = 0; mi < 4; mi++)
#pragma unroll
    for (int i = 0; i < 4; i++) {
      const long row = m0 + wm + mi * 16 + lg * 4 + i;
      const long rb = row * ldc + n0 + wn + lr;
      if (EPI == 0) {
        short* p = (short*)Cout + rb;
#pragma unroll
        for (int nj = 0; nj < 4; nj++) p[nj * 16] = f2b(acc[mi][nj][i] + bv[nj]);
      } else if (EPI == 1) {
        short* p = (short*)Cout + rb;
#pragma unroll
        for (int nj = 0; nj < 4; nj++) p[nj * 16] = f2b(gelu_f(acc[mi][nj][i] + bv[nj]));
      } else if (EPI == 2) {
        float* p = (float*)Cout + rb;
        const float* rp = resF + rb;
#pragma unroll
        for (int nj = 0; nj < 4; nj++) p[nj * 16] = acc[mi][nj][i] + bv[nj] + rp[nj * 16];
      } else {
        float* p = (float*)Cout + rb;
        const short* rp = resB + rb;
#pragma unroll
        for (int nj = 0; nj < 4; nj++)
          p[nj * 16] = acc[mi][nj][i] + bv[nj] + b2f(rp[nj * 16]);
      }
    }
}

// ---------------- windowed attention ----------------
__global__ __launch_bounds__(256, 2) void attn_win(const short* __restrict__ QKV,
                                                   short* __restrict__ AO) {
  __shared__ short Vs[64 * 72];
  __shared__ short Ps[64 * 72];
  const int t = threadIdx.x, w = t >> 6, lane = t & 63;
  const int lr = lane & 15, lg = lane >> 4;
  const long base = (long)blockIdx.x * 64 * 1536;
  const long obase = (long)blockIdx.x * 64 * 512;

  for (int h = 0; h < 8; h++) {
    const int co = h * 64;
#pragma unroll
    for (int it = 0; it < 2; it++) {
      int c = t + it * 256;
      int j = c >> 3, d0 = (c & 7) * 8;
      *(bf16x8*)(Vs + j * 72 + d0) =
          *(const bf16x8*)(QKV + base + (long)j * 1536 + 1024 + co + d0);
    }
    __syncthreads();

    bf16x8 qf[2], kf[4][2];
#pragma unroll
    for (int kb = 0; kb < 2; kb++)
      qf[kb] = *(const bf16x8*)(QKV + base + (long)(w * 16 + lr) * 1536 + co + kb * 32 + lg * 8);
#pragma unroll
    for (int nj = 0; nj < 4; nj++)
#pragma unroll
      for (int kb = 0; kb < 2; kb++)
        kf[nj][kb] = *(const bf16x8*)(QKV + base + (long)(nj * 16 + lr) * 1536 + 512 + co +
                                      kb * 32 + lg * 8);

    f32x4 s[4];
#pragma unroll
    for (int nj = 0; nj < 4; nj++) {
      s[nj] = f32x4{0.f, 0.f, 0.f, 0.f};
      s[nj] = __builtin_amdgcn_mfma_f32_16x16x32_bf16(qf[0], kf[nj][0], s[nj], 0, 0, 0);
      s[nj] = __builtin_amdgcn_mfma_f32_16x16x32_bf16(qf[1], kf[nj][1], s[nj], 0, 0, 0);
      s[nj] = s[nj] * 0.125f;
    }

#pragma unroll
    for (int i = 0; i < 4; i++) {
      float mx = fmaxf(fmaxf(s[0][i], s[1][i]), fmaxf(s[2][i], s[3][i]));
#pragma unroll
      for (int off = 1; off < 16; off <<= 1) mx = fmaxf(mx, __shfl_xor(mx, off, 64));
      float sum = 0.f;
#pragma unroll
      for (int nj = 0; nj < 4; nj++) {
        float p = __expf(s[nj][i] - mx);
        s[nj][i] = p;
        sum += p;
      }
#pragma unroll
      for (int off = 1; off < 16; off <<= 1) sum += __shfl_xor(sum, off, 64);
      float inv = 1.f / sum;
#pragma unroll
      for (int nj = 0; nj < 4; nj++) s[nj][i] *= inv;
    }

#pragma unroll
    for (int nj = 0; nj < 4; nj++)
#pragma unroll
      for (int i = 0; i < 4; i++)
        Ps[(w * 16 + lg * 4 + i) * 72 + nj * 16 + lr] = f2b(s[nj][i]);

    bf16x8 pa[2];
#pragma unroll
    for (int kb = 0; kb < 2; kb++)
      pa[kb] = *(const bf16x8*)(Ps + (w * 16 + lr) * 72 + kb * 32 + lg * 8);

    f32x4 o[4];
#pragma unroll
    for (int nb = 0; nb < 4; nb++) o[nb] = f32x4{0.f, 0.f, 0.f, 0.f};
#pragma unroll
    for (int kb = 0; kb < 2; kb++)
#pragma unroll
      for (int nb = 0; nb < 4; nb++) {
        bf16x8 vb;
#pragma unroll
        for (int jj = 0; jj < 8; jj++)
          vb[jj] = Vs[(kb * 32 + lg * 8 + jj) * 72 + nb * 16 + lr];
        o[nb] = __builtin_amdgcn_mfma_f32_16x16x32_bf16(pa[kb], vb, o[nb], 0, 0, 0);
      }

#pragma unroll
    for (int nb = 0; nb < 4; nb++)
#pragma unroll
      for (int i = 0; i < 4; i++)
        AO[obase + (long)(w * 16 + lg * 4 + i) * 512 + co + nb * 16 + lr] = f2b(o[nb][i]);
    __syncthreads();
  }
}

// ---------------- LayerNorm over C=512, one row per wave ----------------
template <int OUTB>
__global__ __launch_bounds__(256, 4) void ln_rows(const float* __restrict__ Y,
                                                  const float* __restrict__ gamma,
                                                  const float* __restrict__ beta,
                                                  short* __restrict__ Hb,
                                                  float* __restrict__ Of) {
  const int w = threadIdx.x >> 6, lane = threadIdx.x & 63;
  const long row = (long)blockIdx.x * 4 + w;
  const float* y = Y + row * 512 + lane * 8;
  f32x4 a = *(const f32x4*)(y);
  f32x4 b = *(const f32x4*)(y + 4);
  float s = a[0] + a[1] + a[2] + a[3] + b[0] + b[1] + b[2] + b[3];
  float s2 = a[0] * a[0] + a[1] * a[1] + a[2] * a[2] + a[3] * a[3] + b[0] * b[0] +
             b[1] * b[1] + b[2] * b[2] + b[3] * b[3];
#pragma unroll
  for (int off = 1; off < 64; off <<= 1) {
    s += __shfl_xor(s, off, 64);
    s2 += __shfl_xor(s2, off, 64);
  }
  float mu = s * (1.f / 512.f);
  float var = s2 * (1.f / 512.f) - mu * mu;
  float rstd = rsqrtf(fmaxf(var, 0.f) + 1e-12f);
  const int c0 = lane * 8;
  f32x4 ga = *(const f32x4*)(gamma + c0), gb = *(const f32x4*)(gamma + c0 + 4);
  f32x4 ba = *(const f32x4*)(beta + c0), bb = *(const f32x4*)(beta + c0 + 4);
  if (OUTB) {
    bf16x8 o;
#pragma unroll
    for (int j = 0; j < 4; j++) o[j] = f2b(ga[j] * ((a[j] - mu) * rstd) + ba[j]);
#pragma unroll
    for (int j = 0; j < 4; j++) o[j + 4] = f2b(gb[j] * ((b[j] - mu) * rstd) + bb[j]);
    *(bf16x8*)(Hb + row * 512 + c0) = o;
  } else {
    f32x4 o0, o1;
#pragma unroll
    for (int j = 0; j < 4; j++) o0[j] = ga[j] * ((a[j] - mu) * rstd) + ba[j];
#pragma unroll
    for (int j = 0; j < 4; j++) o1[j] = gb[j] * ((b[j] - mu) * rstd) + bb[j];
    *(f32x4*)(Of + row * 512 + c0) = o0;
    *(f32x4*)(Of + row * 512 + c0 + 4) = o1;
  }
}

// ---------------- driver ----------------
extern "C" void kernel_launch(void* const* d_in, const int* in_sizes, int n_in,
                              void* d_out, int out_size, void* d_ws, size_t ws_size,
                              hipStream_t stream) {
  (void)in_sizes; (void)n_in; (void)out_size;
  const float* x = (const float*)d_in[0];
  const float* wq = (const float*)d_in[1];
  const float* bq = (const float*)d_in[2];
  const float* wk = (const float*)d_in[3];
  const float* bk = (const float*)d_in[4];
  const float* wv = (const float*)d_in[5];
  const float* bv = (const float*)d_in[6];
  const float* wo = (const float*)d_in[7];
  const float* bo = (const float*)d_in[8];
  const float* g1 = (const float*)d_in[9];
  const float* be1 = (const float*)d_in[10];
  const float* wfc1 = (const float*)d_in[11];
  const float* bfc1 = (const float*)d_in[12];
  const float* wfc2 = (const float*)d_in[13];
  const float* bfc2 = (const float*)d_in[14];
  const float* g2 = (const float*)d_in[15];
  const float* be2 = (const float*)d_in[16];

  const long T = 65536;
  char* ws = (char*)d_ws;

  // ---- weights at offset 0 (~6.3 MiB) ----
  short* WQKVT = (short*)(ws);                 // [1536][512]
  short* WOT = WQKVT + 1536 * 512;             // [512][512]
  short* WFC1T = WOT + 512 * 512;              // [2048][512]
  short* WFC2T = WFC1T + 2048 * 512;           // [512][2048]
  float* BQKV = (float*)(WFC2T + 512 * 2048);  // [1536]
  size_t woff = ((size_t)((char*)(BQKV + 1536) - ws) + 255) & ~(size_t)255;

  // ---- adaptive chunking (Tc multiple of 128) ----
  size_t avail = (ws_size > woff) ? (ws_size - woff) : 0;
  long Tc = T;
  while (Tc > 128 && (size_t)Tc * 7168 > avail) Tc >>= 1;
  const long nch = T / Tc;

  char* R0 = ws + woff;               // QKV bf16 [Tc][1536] / Y1 f32 / FF1 bf16 [Tc][2048]
  char* R1 = R0 + (size_t)Tc * 4096;  // XB bf16 / AO bf16 / Y2 f32
  char* R2 = R1 + (size_t)Tc * 2048;  // H bf16

  short* QKV = (short*)R0;
  float* Y1 = (float*)R0;
  short* FF1 = (short*)R0;
  short* XB = (short*)R1;
  short* AO = (short*)R1;
  float* Y2 = (float*)R1;
  short* H = (short*)R2;

  // ---- pack weights (tiled transposes, both sides coalesced) ----
  transpose_cvt_t<<<dim3(16, 16), 256, 0, stream>>>(wq, WQKVT, 512, 512);
  transpose_cvt_t<<<dim3(16, 16), 256, 0, stream>>>(wk, WQKVT + 512 * 512, 512, 512);
  transpose_cvt_t<<<dim3(16, 16), 256, 0, stream>>>(wv, WQKVT + 1024 * 512, 512, 512);
  transpose_cvt_t<<<dim3(16, 16), 256, 0, stream>>>(wo, WOT, 512, 512);
  transpose_cvt_t<<<dim3(64, 16), 256, 0, stream>>>(wfc1, WFC1T, 512, 2048);
  transpose_cvt_t<<<dim3(16, 64), 256, 0, stream>>>(wfc2, WFC2T, 2048, 512);
  pack_bias3<<<6, 256, 0, stream>>>(bq, bk, bv, BQKV);

  for (long c = 0; c < nch; c++) {
    const long t0 = c * Tc;
    const int mb = (int)(Tc / 128);
    cvt_bf16_vec<<<(int)(Tc / 4), 256, 0, stream>>>(x + t0 * 512, XB, Tc * 512);
    gemm_bt<0><<<mb * 12, 256, 0, stream>>>(XB, WQKVT, BQKV, nullptr, nullptr,
                                            (void*)QKV, 512, 1536, 12);
    attn_win<<<(int)(Tc / 64), 256, 0, stream>>>(QKV, AO);
    gemm_bt<2><<<mb * 4, 256, 0, stream>>>(AO, WOT, bo, x + t0 * 512, nullptr,
                                           (void*)Y1, 512, 512, 4);
    ln_rows<1><<<(int)(Tc / 4), 256, 0, stream>>>(Y1, g1, be1, H, nullptr);
    gemm_bt<1><<<mb * 16, 256, 0, stream>>>(H, WFC1T, bfc1, nullptr, nullptr,
                                            (void*)FF1, 512, 2048, 16);
    gemm_bt<3><<<mb * 4, 256, 0, stream>>>(FF1, WFC2T, bfc2, nullptr, H, (void*)Y2,
                                           2048, 512, 4);
    ln_rows<0><<<(int)(Tc / 4), 256, 0, stream>>>(Y2, g2, be2, nullptr,
                                                  (float*)d_out + t0 * 512);
  }
}

// Round 8
// 771.499 us; speedup vs baseline: 1.1281x; 1.0623x over previous
//
#include <hip/hip_runtime.h>

typedef __attribute__((ext_vector_type(8))) short bf16x8;
typedef __attribute__((ext_vector_type(4))) float f32x4;

__device__ __forceinline__ short f2b(float f) {
  unsigned u = __builtin_bit_cast(unsigned, f);
  unsigned r = (u + 0x7FFFu + ((u >> 16) & 1u)) >> 16;
  return (short)r;
}
__device__ __forceinline__ float b2f(short s) {
  unsigned u = ((unsigned)(unsigned short)s) << 16;
  return __builtin_bit_cast(float, u);
}

__device__ __forceinline__ void gload16(const void* g, void* l) {
  __builtin_amdgcn_global_load_lds(
      (const __attribute__((address_space(1))) void*)g,
      (__attribute__((address_space(3))) void*)l, 16, 0, 0);
}

// tanh-form GELU: |err| vs erf-GELU < ~5e-4, far under bf16 rounding.
__device__ __forceinline__ float gelu_f(float v) {
  float u = v * (0.7978845608f + 0.0356774081f * v * v);
  float a = fabsf(u);
  float e = __expf(-2.f * a);
  float t = (1.f - e) * __builtin_amdgcn_rcpf(1.f + e);
  t = (u < 0.f) ? -t : t;
  return 0.5f * v * (1.f + t);
}

// ---------------- packing kernels ----------------
__global__ void cvt_bf16_vec(const float* __restrict__ src, short* __restrict__ dst, long n) {
  long i = ((long)blockIdx.x * 256 + threadIdx.x) * 8;
  if (i >= n) return;
  f32x4 a = *(const f32x4*)(src + i);
  f32x4 b = *(const f32x4*)(src + i + 4);
  bf16x8 o;
#pragma unroll
  for (int j = 0; j < 4; j++) o[j] = f2b(a[j]);
#pragma unroll
  for (int j = 0; j < 4; j++) o[j + 4] = f2b(b[j]);
  *(bf16x8*)(dst + i) = o;
}

// dst[n][k] = bf16(src[k][n]); both sides coalesced via 32x33 LDS tile.
__global__ void transpose_cvt_t(const float* __restrict__ src, short* __restrict__ dst,
                                int K, int N) {
  __shared__ float tile[32][33];
  const int n0 = blockIdx.x * 32, k0 = blockIdx.y * 32;
  const int j = threadIdx.x & 31, i0 = threadIdx.x >> 5;
#pragma unroll
  for (int r = 0; r < 4; r++) {
    int i = i0 + r * 8;
    tile[i][j] = src[(long)(k0 + i) * N + n0 + j];
  }
  __syncthreads();
#pragma unroll
  for (int r = 0; r < 4; r++) {
    int i = i0 + r * 8;
    dst[(long)(n0 + i) * K + k0 + j] = f2b(tile[j][i]);
  }
}

__global__ void pack_bias3(const float* __restrict__ b0, const float* __restrict__ b1,
                           const float* __restrict__ b2, float* __restrict__ out) {
  int t = blockIdx.x * 256 + threadIdx.x;
  if (t >= 1536) return;
  out[t] = (t < 512) ? b0[t] : ((t < 1024) ? b1[t - 512] : b2[t - 1024]);
}

// ---------------- 256x256 8-phase GEMM: C = A[M][K] @ Bt[N][K]^T ------------
// BK=64, 8 waves (2M x 4N), per-wave 128x64 output, 2-dbuf LDS (128 KiB dyn).
// Per tile: 4 phases (one 32x64-row C-quadrant, 16 MFMA each); B-frags read
// once per tile (phase 0), register-resident. Stage 1 half-tile (2 gload_lds)
// per phase: ph0 A0(t+1), ph1 A1(t+1), ph2 B0(t+2), ph3 B1(t+2). vmcnt(4)
// once per tile before the tile-final barrier (B(t+2) stays in flight).
// Swizzle: LDS[row][c] = global[row][c^(row&7)] via pre-swizzled per-lane
// global source (linear gload_lds dest); reads use the same XOR -> 2-way.
// EPI 0: bf16 v+bias | 1: bf16 gelu(v+bias) | 2: f32 v+bias+resF | 3: f32
// v+bias+resB (bf16 residual).
template <int EPI>
__global__ __launch_bounds__(512, 1) void gemm256(
    const short* __restrict__ A, const short* __restrict__ Bt,
    const float* __restrict__ bias, const float* __restrict__ resF,
    const short* __restrict__ resB, void* __restrict__ Cout, int K, int ldc, int gxN) {
  extern __shared__ short lds[];  // A: [0,32768) shorts (2 dbuf), B: [32768,65536)
  const int t = threadIdx.x;
  const int lane = t & 63, w = t >> 6;
  const int lr = lane & 15, lg = lane >> 4;
  const int wm = w >> 2, wn = w & 3;

  const int nwg = gridDim.x, orig = blockIdx.x;
  const int q8 = nwg >> 3, r8 = nwg & 7, xcd = orig & 7, idx = orig >> 3;
  const int swz = (xcd < r8 ? xcd * (q8 + 1) : r8 * (q8 + 1) + (xcd - r8) * q8) + idx;
  const long m0 = (long)(swz / gxN) * 256;
  const int n0 = (swz % gxN) * 256;

  f32x4 acc[8][4];
#pragma unroll
  for (int i = 0; i < 8; i++)
#pragma unroll
    for (int j = 0; j < 4; j++) acc[i][j] = f32x4{0.f, 0.f, 0.f, 0.f};

  // staging: thread t -> dest (row = t>>3 [+64 for load1], chunk = t&7) of a
  // 128x64 half-tile; source chunk = (t&7)^(row&7), row&7 == (t>>3)&7.
  const int srow = t >> 3;
  const int sch = (t & 7) ^ (srow & 7);
  const short* sA = A + (m0 + srow) * (long)K + sch * 8;
  const short* sB = Bt + ((long)n0 + srow) * K + sch * 8;
  const long r64 = (long)64 * K;

#define STG_A(tt, h)                                                     \
  {                                                                      \
    short* d_ = lds + ((tt) & 1) * 16384 + (h) * 8192 + t * 8;           \
    const short* s_ = sA + (h) * 2 * r64 + (long)(tt) * 64;              \
    gload16(s_, d_);                                                     \
    gload16(s_ + r64, d_ + 4096);                                        \
  }
#define STG_B(tt, h)                                                     \
  {                                                                      \
    short* d_ = lds + 32768 + ((tt) & 1) * 16384 + (h) * 8192 + t * 8;   \
    const short* s_ = sB + (h) * 2 * r64 + (long)(tt) * 64;              \
    gload16(s_, d_);                                                     \
    gload16(s_ + r64, d_ + 4096);                                        \
  }

  // read offsets: chunk (ks*4+lg) ^ (lr&7), row stride 64 shorts (128 B)
  const int xsw0 = (lg ^ (lr & 7)) * 8;
  const int xsw1 = ((4 + lg) ^ (lr & 7)) * 8;
  const int aRow0 = (wm * 128 + lr) * 64;
  const int bRow0 = 32768 + (wn * 64 + lr) * 64;

#define BAR                                  \
  {                                          \
    __builtin_amdgcn_sched_barrier(0);       \
    __builtin_amdgcn_s_barrier();            \
    __builtin_amdgcn_sched_barrier(0);       \
  }

  const int NT = K >> 6;  // >= 8 for all shapes here
  STG_A(0, 0) STG_A(0, 1) STG_B(0, 0) STG_B(0, 1) STG_B(1, 0) STG_B(1, 1)
  asm volatile("s_waitcnt vmcnt(4)" ::: "memory");
  BAR

  bf16x8 b[4][2];

#define PHASE_Q(Q, STAGE_STMT, PRE_BAR2)                                       \
  {                                                                            \
    bf16x8 aq[2][2];                                                           \
    _Pragma("unroll") for (int mi = 0; mi < 2; mi++) {                         \
      aq[mi][0] =                                                              \
          *(const bf16x8*)(lds + aRow0 + dA + ((Q) * 32 + mi * 16) * 64 + xsw0); \
      aq[mi][1] =                                                              \
          *(const bf16x8*)(lds + aRow0 + dA + ((Q) * 32 + mi * 16) * 64 + xsw1); \
    }                                                                          \
    STAGE_STMT                                                                 \
    BAR                                                                        \
    __builtin_amdgcn_s_setprio(1);                                             \
    _Pragma("unroll") for (int mi = 0; mi < 2; mi++)                           \
        _Pragma("unroll") for (int nj = 0; nj < 4; nj++) {                     \
      acc[(Q) * 2 + mi][nj] = __builtin_amdgcn_mfma_f32_16x16x32_bf16(         \
          aq[mi][0], b[nj][0], acc[(Q) * 2 + mi][nj], 0, 0, 0);                \
      acc[(Q) * 2 + mi][nj] = __builtin_amdgcn_mfma_f32_16x16x32_bf16(         \
          aq[mi][1], b[nj][1], acc[(Q) * 2 + mi][nj], 0, 0, 0);                \
    }                                                                          \
    __builtin_amdgcn_s_setprio(0);                                             \
    PRE_BAR2                                                                   \
    BAR                                                                        \
  }

  for (int tt = 0; tt < NT; ++tt) {
    const int dA = (tt & 1) * 16384;
    // ---- phase 0: read all B-frags + A quadrant 0; stage A0(tt+1) ----
    {
#pragma unroll
      for (int nj = 0; nj < 4; nj++) {
        b[nj][0] = *(const bf16x8*)(lds + bRow0 + dA + nj * 1024 + xsw0);
        b[nj][1] = *(const bf16x8*)(lds + bRow0 + dA + nj * 1024 + xsw1);
      }
      bf16x8 aq[2][2];
#pragma unroll
      for (int mi = 0; mi < 2; mi++) {
        aq[mi][0] = *(const bf16x8*)(lds + aRow0 + dA + (mi * 16) * 64 + xsw0);
        aq[mi][1] = *(const bf16x8*)(lds + aRow0 + dA + (mi * 16) * 64 + xsw1);
      }
      if (tt + 1 < NT) STG_A(tt + 1, 0)
      BAR
      __builtin_amdgcn_s_setprio(1);
#pragma unroll
      for (int mi = 0; mi < 2; mi++)
#pragma unroll
        for (int nj = 0; nj < 4; nj++) {
          acc[mi][nj] = __builtin_amdgcn_mfma_f32_16x16x32_bf16(
              aq[mi][0], b[nj][0], acc[mi][nj], 0, 0, 0);
          acc[mi][nj] = __builtin_amdgcn_mfma_f32_16x16x32_bf16(
              aq[mi][1], b[nj][1], acc[mi][nj], 0, 0, 0);
        }
      __builtin_amdgcn_s_setprio(0);
      BAR
    }
    // ---- phase 1: A quadrant 1; stage A1(tt+1) ----
    PHASE_Q(1, { if (tt + 1 < NT) STG_A(tt + 1, 1) }, {})
    // ---- phase 2: A quadrant 2; stage B0(tt+2) ----
    PHASE_Q(2, { if (tt + 2 < NT) STG_B(tt + 2, 0) }, {})
    // ---- phase 3: A quadrant 3; stage B1(tt+2); counted wait ----
    PHASE_Q(3, { if (tt + 2 < NT) STG_B(tt + 2, 1) },
            {
              if (tt + 2 < NT) {
                asm volatile("s_waitcnt vmcnt(4)" ::: "memory");
              } else if (tt + 1 < NT) {
                asm volatile("s_waitcnt vmcnt(0)" ::: "memory");
              }
            })
  }
#undef PHASE_Q
#undef STG_A
#undef STG_B
#undef BAR

  // epilogue: bias hoisted, vectorless 4-col strided writes per (a,i)
  float bv[4];
#pragma unroll
  for (int nj = 0; nj < 4; nj++) bv[nj] = bias[n0 + wn * 64 + nj * 16 + lr];

#pragma unroll
  for (int a = 0; a < 8; a++)
#pragma unroll
    for (int i = 0; i < 4; i++) {
      const long row = m0 + wm * 128 + a * 16 + lg * 4 + i;
      const long rb = row * ldc + n0 + wn * 64 + lr;
      if (EPI == 0) {
        short* p = (short*)Cout + rb;
#pragma unroll
        for (int nj = 0; nj < 4; nj++) p[nj * 16] = f2b(acc[a][nj][i] + bv[nj]);
      } else if (EPI == 1) {
        short* p = (short*)Cout + rb;
#pragma unroll
        for (int nj = 0; nj < 4; nj++) p[nj * 16] = f2b(gelu_f(acc[a][nj][i] + bv[nj]));
      } else if (EPI == 2) {
        float* p = (float*)Cout + rb;
        const float* rp = resF + rb;
#pragma unroll
        for (int nj = 0; nj < 4; nj++) p[nj * 16] = acc[a][nj][i] + bv[nj] + rp[nj * 16];
      } else {
        float* p = (float*)Cout + rb;
        const short* rp = resB + rb;
#pragma unroll
        for (int nj = 0; nj < 4; nj++)
          p[nj * 16] = acc[a][nj][i] + bv[nj] + b2f(rp[nj * 16]);
      }
    }
}

// ---------------- windowed attention ----------------
__global__ __launch_bounds__(256, 2) void attn_win(const short* __restrict__ QKV,
                                                   short* __restrict__ AO) {
  __shared__ short Vs[64 * 72];
  __shared__ short Ps[64 * 72];
  const int t = threadIdx.x, w = t >> 6, lane = t & 63;
  const int lr = lane & 15, lg = lane >> 4;
  const long base = (long)blockIdx.x * 64 * 1536;
  const long obase = (long)blockIdx.x * 64 * 512;

  for (int h = 0; h < 8; h++) {
    const int co = h * 64;
#pragma unroll
    for (int it = 0; it < 2; it++) {
      int c = t + it * 256;
      int j = c >> 3, d0 = (c & 7) * 8;
      *(bf16x8*)(Vs + j * 72 + d0) =
          *(const bf16x8*)(QKV + base + (long)j * 1536 + 1024 + co + d0);
    }
    __syncthreads();

    bf16x8 qf[2], kf[4][2];
#pragma unroll
    for (int kb = 0; kb < 2; kb++)
      qf[kb] = *(const bf16x8*)(QKV + base + (long)(w * 16 + lr) * 1536 + co + kb * 32 + lg * 8);
#pragma unroll
    for (int nj = 0; nj < 4; nj++)
#pragma unroll
      for (int kb = 0; kb < 2; kb++)
        kf[nj][kb] = *(const bf16x8*)(QKV + base + (long)(nj * 16 + lr) * 1536 + 512 + co +
                                      kb * 32 + lg * 8);

    f32x4 s[4];
#pragma unroll
    for (int nj = 0; nj < 4; nj++) {
      s[nj] = f32x4{0.f, 0.f, 0.f, 0.f};
      s[nj] = __builtin_amdgcn_mfma_f32_16x16x32_bf16(qf[0], kf[nj][0], s[nj], 0, 0, 0);
      s[nj] = __builtin_amdgcn_mfma_f32_16x16x32_bf16(qf[1], kf[nj][1], s[nj], 0, 0, 0);
      s[nj] = s[nj] * 0.125f;
    }

#pragma unroll
    for (int i = 0; i < 4; i++) {
      float mx = fmaxf(fmaxf(s[0][i], s[1][i]), fmaxf(s[2][i], s[3][i]));
#pragma unroll
      for (int off = 1; off < 16; off <<= 1) mx = fmaxf(mx, __shfl_xor(mx, off, 64));
      float sum = 0.f;
#pragma unroll
      for (int nj = 0; nj < 4; nj++) {
        float p = __expf(s[nj][i] - mx);
        s[nj][i] = p;
        sum += p;
      }
#pragma unroll
      for (int off = 1; off < 16; off <<= 1) sum += __shfl_xor(sum, off, 64);
      float inv = 1.f / sum;
#pragma unroll
      for (int nj = 0; nj < 4; nj++) s[nj][i] *= inv;
    }

#pragma unroll
    for (int nj = 0; nj < 4; nj++)
#pragma unroll
      for (int i = 0; i < 4; i++)
        Ps[(w * 16 + lg * 4 + i) * 72 + nj * 16 + lr] = f2b(s[nj][i]);

    bf16x8 pa[2];
#pragma unroll
    for (int kb = 0; kb < 2; kb++)
      pa[kb] = *(const bf16x8*)(Ps + (w * 16 + lr) * 72 + kb * 32 + lg * 8);

    f32x4 o[4];
#pragma unroll
    for (int nb = 0; nb < 4; nb++) o[nb] = f32x4{0.f, 0.f, 0.f, 0.f};
#pragma unroll
    for (int kb = 0; kb < 2; kb++)
#pragma unroll
      for (int nb = 0; nb < 4; nb++) {
        bf16x8 vb;
#pragma unroll
        for (int jj = 0; jj < 8; jj++)
          vb[jj] = Vs[(kb * 32 + lg * 8 + jj) * 72 + nb * 16 + lr];
        o[nb] = __builtin_amdgcn_mfma_f32_16x16x32_bf16(pa[kb], vb, o[nb], 0, 0, 0);
      }

#pragma unroll
    for (int nb = 0; nb < 4; nb++)
#pragma unroll
      for (int i = 0; i < 4; i++)
        AO[obase + (long)(w * 16 + lg * 4 + i) * 512 + co + nb * 16 + lr] = f2b(o[nb][i]);
    __syncthreads();
  }
}

// ---------------- LayerNorm over C=512, one row per wave ----------------
template <int OUTB>
__global__ __launch_bounds__(256, 4) void ln_rows(const float* __restrict__ Y,
                                                  const float* __restrict__ gamma,
                                                  const float* __restrict__ beta,
                                                  short* __restrict__ Hb,
                                                  float* __restrict__ Of) {
  const int w = threadIdx.x >> 6, lane = threadIdx.x & 63;
  const long row = (long)blockIdx.x * 4 + w;
  const float* y = Y + row * 512 + lane * 8;
  f32x4 a = *(const f32x4*)(y);
  f32x4 b = *(const f32x4*)(y + 4);
  float s = a[0] + a[1] + a[2] + a[3] + b[0] + b[1] + b[2] + b[3];
  float s2 = a[0] * a[0] + a[1] * a[1] + a[2] * a[2] + a[3] * a[3] + b[0] * b[0] +
             b[1] * b[1] + b[2] * b[2] + b[3] * b[3];
#pragma unroll
  for (int off = 1; off < 64; off <<= 1) {
    s += __shfl_xor(s, off, 64);
    s2 += __shfl_xor(s2, off, 64);
  }
  float mu = s * (1.f / 512.f);
  float var = s2 * (1.f / 512.f) - mu * mu;
  float rstd = rsqrtf(fmaxf(var, 0.f) + 1e-12f);
  const int c0 = lane * 8;
  f32x4 ga = *(const f32x4*)(gamma + c0), gb = *(const f32x4*)(gamma + c0 + 4);
  f32x4 ba = *(const f32x4*)(beta + c0), bb = *(const f32x4*)(beta + c0 + 4);
  if (OUTB) {
    bf16x8 o;
#pragma unroll
    for (int j = 0; j < 4; j++) o[j] = f2b(ga[j] * ((a[j] - mu) * rstd) + ba[j]);
#pragma unroll
    for (int j = 0; j < 4; j++) o[j + 4] = f2b(gb[j] * ((b[j] - mu) * rstd) + bb[j]);
    *(bf16x8*)(Hb + row * 512 + c0) = o;
  } else {
    f32x4 o0, o1;
#pragma unroll
    for (int j = 0; j < 4; j++) o0[j] = ga[j] * ((a[j] - mu) * rstd) + ba[j];
#pragma unroll
    for (int j = 0; j < 4; j++) o1[j] = gb[j] * ((b[j] - mu) * rstd) + bb[j];
    *(f32x4*)(Of + row * 512 + c0) = o0;
    *(f32x4*)(Of + row * 512 + c0 + 4) = o1;
  }
}

// ---------------- driver ----------------
extern "C" void kernel_launch(void* const* d_in, const int* in_sizes, int n_in,
                              void* d_out, int out_size, void* d_ws, size_t ws_size,
                              hipStream_t stream) {
  (void)in_sizes; (void)n_in; (void)out_size;
  const float* x = (const float*)d_in[0];
  const float* wq = (const float*)d_in[1];
  const float* bq = (const float*)d_in[2];
  const float* wk = (const float*)d_in[3];
  const float* bk = (const float*)d_in[4];
  const float* wv = (const float*)d_in[5];
  const float* bv = (const float*)d_in[6];
  const float* wo = (const float*)d_in[7];
  const float* bo = (const float*)d_in[8];
  const float* g1 = (const float*)d_in[9];
  const float* be1 = (const float*)d_in[10];
  const float* wfc1 = (const float*)d_in[11];
  const float* bfc1 = (const float*)d_in[12];
  const float* wfc2 = (const float*)d_in[13];
  const float* bfc2 = (const float*)d_in[14];
  const float* g2 = (const float*)d_in[15];
  const float* be2 = (const float*)d_in[16];

  const long T = 65536;
  char* ws = (char*)d_ws;

  // ---- weights at offset 0 (~6.3 MiB) ----
  short* WQKVT = (short*)(ws);                 // [1536][512]
  short* WOT = WQKVT + 1536 * 512;             // [512][512]
  short* WFC1T = WOT + 512 * 512;              // [2048][512]
  short* WFC2T = WFC1T + 2048 * 512;           // [512][2048]
  float* BQKV = (float*)(WFC2T + 512 * 2048);  // [1536]
  size_t woff = ((size_t)((char*)(BQKV + 1536) - ws) + 255) & ~(size_t)255;

  // ---- adaptive chunking (Tc multiple of 256) ----
  size_t avail = (ws_size > woff) ? (ws_size - woff) : 0;
  long Tc = T;
  while (Tc > 256 && (size_t)Tc * 7168 > avail) Tc >>= 1;
  const long nch = T / Tc;

  char* R0 = ws + woff;               // QKV bf16 [Tc][1536] / Y1 f32 / FF1 bf16 [Tc][2048]
  char* R1 = R0 + (size_t)Tc * 4096;  // XB bf16 / AO bf16 / Y2 f32
  char* R2 = R1 + (size_t)Tc * 2048;  // H bf16

  short* QKV = (short*)R0;
  float* Y1 = (float*)R0;
  short* FF1 = (short*)R0;
  short* XB = (short*)R1;
  short* AO = (short*)R1;
  float* Y2 = (float*)R1;
  short* H = (short*)R2;

  // ---- pack weights (tiled transposes, both sides coalesced) ----
  transpose_cvt_t<<<dim3(16, 16), 256, 0, stream>>>(wq, WQKVT, 512, 512);
  transpose_cvt_t<<<dim3(16, 16), 256, 0, stream>>>(wk, WQKVT + 512 * 512, 512, 512);
  transpose_cvt_t<<<dim3(16, 16), 256, 0, stream>>>(wv, WQKVT + 1024 * 512, 512, 512);
  transpose_cvt_t<<<dim3(16, 16), 256, 0, stream>>>(wo, WOT, 512, 512);
  transpose_cvt_t<<<dim3(64, 16), 256, 0, stream>>>(wfc1, WFC1T, 512, 2048);
  transpose_cvt_t<<<dim3(16, 64), 256, 0, stream>>>(wfc2, WFC2T, 2048, 512);
  pack_bias3<<<6, 256, 0, stream>>>(bq, bk, bv, BQKV);

  const size_t LDSB = 131072;
  for (long c = 0; c < nch; c++) {
    const long t0 = c * Tc;
    const int mb = (int)(Tc / 256);
    cvt_bf16_vec<<<(int)(Tc / 4), 256, 0, stream>>>(x + t0 * 512, XB, Tc * 512);
    gemm256<0><<<mb * 6, 512, LDSB, stream>>>(XB, WQKVT, BQKV, nullptr, nullptr,
                                              (void*)QKV, 512, 1536, 6);
    attn_win<<<(int)(Tc / 64), 256, 0, stream>>>(QKV, AO);
    gemm256<2><<<mb * 2, 512, LDSB, stream>>>(AO, WOT, bo, x + t0 * 512, nullptr,
                                              (void*)Y1, 512, 512, 2);
    ln_rows<1><<<(int)(Tc / 4), 256, 0, stream>>>(Y1, g1, be1, H, nullptr);
    gemm256<1><<<mb * 8, 512, LDSB, stream>>>(H, WFC1T, bfc1, nullptr, nullptr,
                                              (void*)FF1, 512, 2048, 8);
    gemm256<3><<<mb * 2, 512, LDSB, stream>>>(FF1, WFC2T, bfc2, nullptr, H, (void*)Y2,
                                              2048, 512, 2);
    ln_rows<0><<<(int)(Tc / 4), 256, 0, stream>>>(Y2, g2, be2, nullptr,
                                                  (float*)d_out + t0 * 512);
  }
}